// Round 12
// baseline (222.449 us; speedup 1.0000x reference)
//
#include <hip/hip_runtime.h>

// D-FINE post-processor, SINGLE dispatch, filter-optimal geometry + fused
// select via last-arriver:
//   - B*BPB = 2048 blocks x 256 threads (8 light blocks/CU -> streaming-BW
//     geometry). Block (b,slice) filters a contiguous 2500-float4 slice of
//     batch b's logits: two 5-deep load bursts (sched_barrier), hits
//     (logit > THR) scattered to a PRIVATE global segment (no contention,
//     no memset needed), true count -> scnt[blk].
//   - Last-arriver select: after threadfence+sync, one lane does a
//     device-scope atomicAdd(&arrive[b],1). The block seeing (ret&7)==7 is
//     the 8th arriver (holds for ANY stale initial value -> replay-safe,
//     no zeroing) and becomes batch b's selector: segments -> LDS,
//     rank-based selection (count-of-greater on packed (key<<32)|~idx =
//     exact jax.lax.top_k tie semantics), decode + emit. Output independent
//     of which block wins -> deterministic.
//   - FALLBACK: exact histogram selection over the batch if bound check
//     (every m_s <= seg, K <= total <= CAPL) fails.
// Output (float32): labels [B*K] | boxes [B*K*4] | scores [B*K]

typedef float f32x4 __attribute__((ext_vector_type(4)));

constexpr int   NT    = 256;    // threads per block
constexpr int   BPB   = 8;      // blocks (slices/segments) per batch
constexpr int   SEG   = 512;    // slots per segment (expect ~82 hits)
constexpr int   CAPL  = 2048;   // per-batch candidate cap in LDS (16 KB)
constexpr int   NBINS = 4096;
constexpr float THR   = 2.4f;   // static pre-filter (fallback makes it safe)

__device__ __forceinline__ unsigned f2key(float f) {
    unsigned u = __float_as_uint(f);
    return (u & 0x80000000u) ? ~u : (u | 0x80000000u);
}
__device__ __forceinline__ float key2f(unsigned k) {
    unsigned u = (k & 0x80000000u) ? (k & 0x7FFFFFFFu) : ~k;
    return __uint_as_float(u);
}
__device__ __forceinline__ unsigned long long packkv(unsigned key, unsigned idx) {
    return ((unsigned long long)key << 32) | (unsigned long long)(0xFFFFFFFFu - idx);
}

__device__ __forceinline__ void consume1(
    float x, unsigned idx, unsigned* lcnt, unsigned long long* segp, int seg)
{
    if (x > THR) {
        unsigned p = atomicAdd(lcnt, 1u);                 // LDS counter
        if (p < (unsigned)seg) segp[p] = packkv(f2key(x), idx);
    }
}
__device__ __forceinline__ void consume4(
    float4 v, int i4, unsigned* lcnt, unsigned long long* segp, int seg)
{
    float mx = fmaxf(fmaxf(v.x, v.y), fmaxf(v.z, v.w));
    if (mx > THR) {
        unsigned bi = (unsigned)(4 * i4);
        consume1(v.x, bi + 0, lcnt, segp, seg);
        consume1(v.y, bi + 1, lcnt, segp, seg);
        consume1(v.z, bi + 2, lcnt, segp, seg);
        consume1(v.w, bi + 3, lcnt, segp, seg);
    }
}

template<int U>
__device__ __forceinline__ void filter_phase(
    const float4* __restrict__ base4, int lo, int off, int hi,
    unsigned* lcnt, unsigned long long* segp, int seg, int tid)
{
    float4 v[U];
    #pragma unroll
    for (int j = 0; j < U; ++j) {
        int i4 = lo + off + j * NT + tid;
        v[j] = base4[(i4 < hi) ? i4 : (hi - 1)];          // clamped, predicated use
    }
    __builtin_amdgcn_sched_barrier(0);                    // burst stays a burst
    #pragma unroll
    for (int j = 0; j < U; ++j) {
        int i4 = lo + off + j * NT + tid;
        if (i4 < hi) consume4(v[j], i4, lcnt, segp, seg);
    }
}

__global__ __launch_bounds__(NT) void dfine_fused_kernel(
    const float* __restrict__ logits,        // [B, Q*C]
    const float* __restrict__ pboxes,        // [B, Q, 4]
    const float* __restrict__ sizes,         // [B, 2]
    unsigned* __restrict__ arrive,           // [B]      (never zeroed; &7 trick)
    unsigned* __restrict__ scnt,             // [B*BPB]  (overwritten each call)
    unsigned long long* __restrict__ candG,  // [B*BPB*seg]
    float* __restrict__ out,
    int B, int Q, int C, int K, int N4, int chunk4, int seg)
{
    const int blk   = blockIdx.x;
    const int b     = blk >> 3;              // BPB = 8
    const int slice = blk & 7;
    const int tid   = threadIdx.x;
    const int N     = Q * C;
    const int lo    = slice * chunk4;
    const int hi    = (lo + chunk4 < N4) ? (lo + chunk4) : N4;
    const float4* __restrict__ base4 = reinterpret_cast<const float4*>(logits + (long long)b * N);
    unsigned long long* __restrict__ segp = candG + (long long)blk * seg;

    // LDS: candS (16 KB) overlaid by fallback hist; + partial + scalars (~17.4 KB)
    __shared__ unsigned long long candS[CAPL];
    __shared__ unsigned partial[NT];
    __shared__ unsigned msz[BPB], moff[BPB];
    __shared__ unsigned lcnt, candCount, threshBin, selret;
    __shared__ int hot;

    if (tid == 0) lcnt = 0u;
    __syncthreads();

    // ---- filter my slice: two 5-deep bursts + generic tail ----
    filter_phase<5>(base4, lo, 0,      hi, &lcnt, segp, seg, tid);
    filter_phase<5>(base4, lo, 5 * NT, hi, &lcnt, segp, seg, tid);
    for (int i4 = lo + 10 * NT + tid; i4 < hi; i4 += NT)   // no-op at chunk4=2500
        consume4(base4[i4], i4, &lcnt, segp, seg);
    __syncthreads();

    if (tid == 0) scnt[blk] = lcnt;          // true count (> seg => fallback)
    __threadfence();                          // each thread releases its stores
    __syncthreads();
    if (tid == 0)
        selret = atomicAdd(&arrive[b], 1u);  // device-scope arrival
    __syncthreads();
    if (((selret) & 7u) != 7u) return;       // 8 consecutive returns: exactly one wins

    // ================= selector for batch b (256 threads) =================
    __threadfence();                          // acquire side
    if (tid < BPB) msz[tid] = scnt[b * BPB + tid];
    __syncthreads();
    if (tid == 0) {
        unsigned tot = 0; int ok = 1;
        #pragma unroll
        for (int s = 0; s < BPB; ++s) {
            moff[s] = tot;
            if (msz[s] > (unsigned)seg) ok = 0;
            tot += msz[s];
        }
        candCount = tot;
        hot = ok && tot >= (unsigned)K && tot <= (unsigned)CAPL;
    }
    __syncthreads();

    int n;
    if (hot) {
        n = (int)candCount;
        #pragma unroll
        for (int s = 0; s < BPB; ++s) {
            const unsigned long long* sp = candG + (long long)(b * BPB + s) * seg;
            unsigned m = msz[s], o = moff[s];
            for (unsigned i = tid; i < m; i += NT) candS[o + i] = sp[i];
        }
        __syncthreads();
    } else {
        // ---- fallback: exact histogram selection (hist overlays candS) ----
        unsigned* hist = reinterpret_cast<unsigned*>(candS);
        const float* __restrict__ lg = logits + (long long)b * N;
        for (int i = tid; i < NBINS; i += NT) hist[i] = 0u;
        if (tid == 0) candCount = 0u;
        __syncthreads();
        for (int i = tid; i < N; i += NT)
            atomicAdd(&hist[f2key(lg[i]) >> 20], 1u);
        __syncthreads();
        {
            const int BPT = NBINS / NT;                  // 16
            unsigned s = 0;
            #pragma unroll
            for (int m = 0; m < BPT; ++m) s += hist[tid * BPT + m];
            partial[tid] = s;
        }
        __syncthreads();
        if (tid < 64) {
            const int PPG = NT / 64;                     // 4
            unsigned gs = 0;
            #pragma unroll
            for (int m = 0; m < PPG; ++m) gs += partial[tid * PPG + m];
            unsigned pre = gs;
            #pragma unroll
            for (int off = 1; off < 64; off <<= 1) {
                unsigned t = __shfl_up(pre, off);
                if (tid >= off) pre += t;
            }
            unsigned total = __shfl(pre, 63);
            unsigned suf   = total - (pre - gs);
            unsigned long long m1 = __ballot(suf >= (unsigned)K);
            int g = 63 - __clzll(m1);
            unsigned above = total - __shfl(pre, g);
            unsigned hv = hist[g * 64 + tid];
            unsigned pre2 = hv;
            #pragma unroll
            for (int off = 1; off < 64; off <<= 1) {
                unsigned t = __shfl_up(pre2, off);
                if (tid >= off) pre2 += t;
            }
            unsigned total2 = __shfl(pre2, 63);
            unsigned suf2   = above + total2 - (pre2 - hv);
            unsigned long long m2 = __ballot(suf2 >= (unsigned)K);
            int l2 = 63 - __clzll(m2);
            if (tid == 0) threshBin = (unsigned)(g * 64 + l2);
        }
        __syncthreads();
        const unsigned tb = threshBin;
        __syncthreads();                                  // hist reads done
        for (int i = tid; i < N; i += NT) {               // gather overwrites hist region
            unsigned k = f2key(lg[i]);
            if ((k >> 20) >= tb) {
                unsigned p = atomicAdd(&candCount, 1u);
                if (p < (unsigned)CAPL) candS[p] = packkv(k, (unsigned)i);
            }
        }
        __syncthreads();
        n = (int)min(candCount, (unsigned)CAPL);
    }

    // ---- rank-based selection + emit ----
    const int BK = B * K;
    float* __restrict__ out_labels = out;
    float* __restrict__ out_boxes  = out + BK;
    float* __restrict__ out_scores = out + (long long)BK * 5;
    const float s0 = sizes[2 * b];
    const float s1 = sizes[2 * b + 1];

    for (int t = tid; t < n; t += NT) {
        unsigned long long my = candS[t];
        int r = 0;
        for (int j = 0; j < n; ++j) r += (candS[j] > my);  // packed keys unique
        if (r < K) {
            unsigned key = (unsigned)(my >> 32);
            unsigned idx = 0xFFFFFFFFu - (unsigned)(my & 0xFFFFFFFFull);
            float logit = key2f(key);
            float score = 1.0f / (1.0f + expf(-logit));
            int label = (int)(idx % (unsigned)C);
            int q     = (int)(idx / (unsigned)C);
            float4 bp = *reinterpret_cast<const float4*>(pboxes + ((long long)b * Q + q) * 4);
            int o = b * K + r;
            out_labels[o] = (float)label;
            out_scores[o] = score;
            float4 bb;
            bb.x = (bp.x - 0.5f * bp.z) * s0;
            bb.y = (bp.y - 0.5f * bp.w) * s1;
            bb.z = (bp.x + 0.5f * bp.z) * s0;
            bb.w = (bp.y + 0.5f * bp.w) * s1;
            *reinterpret_cast<float4*>(out_boxes + 4LL * o) = bb;
        }
    }
}

extern "C" void kernel_launch(void* const* d_in, const int* in_sizes, int n_in,
                              void* d_out, int out_size, void* d_ws, size_t ws_size,
                              hipStream_t stream) {
    const float* logits = (const float*)d_in[0];
    const float* pboxes = (const float*)d_in[1];
    const float* sizes  = (const float*)d_in[2];

    const int B = in_sizes[2] / 2;                 // 256
    const int Q = in_sizes[1] / (4 * B);           // 1000
    const int C = in_sizes[0] / (B * Q);           // 80
    const int K = out_size / (6 * B);              // 300
    const int N = Q * C;
    const int N4 = N / 4;
    const int chunk4 = (N4 + BPB - 1) / BPB;       // 2500
    const int NSEGS = B * BPB;

    // workspace: arrive[B] | scnt[B*BPB] | candG[B*BPB*seg]  (no zeroing ever)
    unsigned* arrive = (unsigned*)d_ws;
    unsigned* scnt   = arrive + B;
    size_t cand_off  = (((size_t)(B + NSEGS) * sizeof(unsigned) + 255) & ~(size_t)255);
    unsigned long long* candG = (unsigned long long*)((char*)d_ws + cand_off);
    long long avail = (long long)ws_size - (long long)cand_off;
    int seg = (avail > 0) ? (int)(avail / ((long long)NSEGS * 8)) : 0;
    if (seg > SEG) seg = SEG;
    if (seg < 0) seg = 0;
    // seg too small => msz > seg => selector falls back (slow but correct)

    dfine_fused_kernel<<<NSEGS, NT, 0, stream>>>(
        logits, pboxes, sizes, arrive, scnt, candG,
        (float*)d_out, B, Q, C, K, N4, chunk4, seg);
}

// Round 13
// 36.066 us; speedup vs baseline: 6.1678x; 6.1678x over previous
//
#include <hip/hip_runtime.h>

// D-FINE post-processor, SINGLE fused kernel: one block per batch (256 x 1024).
//   Filter: software-pipelined register bursts, compiler-scheduled loads
//     (SGPR-base addressing preserved), group order pinned by sched_barrier:
//       issue A(7) | issue B(7) | consume A | issue C(6) | consume B | consume C
//     -> the memory queue never fully drains between phases. Hits (logit > THR)
//     compact into LDS cand[] via an LDS counter. {x > THR} is a prefix of the
//     descending order, so if K <= n <= CAPL the top-K is provably contained.
//   Select: rank-based (count-of-greater over packed (key<<32)|~idx keys =
//     exact jax.lax.top_k tie semantics, broadcast LDS reads), scatter-emit
//     by rank.
//   Fallback: exact in-kernel 4096-bin histogram selection if the bound check
//     fails (any input distribution stays correct).
// __launch_bounds__(1024, 4): we launch exactly 1 block/CU, so allow the full
// 128-VGPR budget (bare launch_bounds made the compiler target 64 and shrink
// the bursts -- R4/R12 evidence).
// Output (float32): labels [B*K] | boxes [B*K*4] | scores [B*K]

constexpr int   NT    = 1024;
constexpr int   NBINS = 4096;
constexpr int   CAPL  = 4096;   // LDS candidate capacity
constexpr float THR   = 2.4f;   // static pre-filter (fallback makes it safe)

__device__ __forceinline__ unsigned f2key(float f) {
    unsigned u = __float_as_uint(f);
    return (u & 0x80000000u) ? ~u : (u | 0x80000000u);
}
__device__ __forceinline__ float key2f(unsigned k) {
    unsigned u = (k & 0x80000000u) ? (k & 0x7FFFFFFFu) : ~k;
    return __uint_as_float(u);
}
__device__ __forceinline__ unsigned long long packkv(unsigned key, unsigned idx) {
    return ((unsigned long long)key << 32) | (unsigned long long)(0xFFFFFFFFu - idx);
}

__device__ __forceinline__ void consume1(
    float x, unsigned idx, unsigned* lcnt, unsigned long long* cand)
{
    if (x > THR) {
        unsigned p = atomicAdd(lcnt, 1u);
        if (p < (unsigned)CAPL) cand[p] = packkv(f2key(x), idx);
    }
}
__device__ __forceinline__ void consume4(
    float4 v, int i4, int N4, unsigned* lcnt, unsigned long long* cand)
{
    if (i4 < N4) {
        float mx = fmaxf(fmaxf(v.x, v.y), fmaxf(v.z, v.w));
        if (mx > THR) {
            unsigned bi = (unsigned)(4 * i4);
            consume1(v.x, bi + 0, lcnt, cand);
            consume1(v.y, bi + 1, lcnt, cand);
            consume1(v.z, bi + 2, lcnt, cand);
            consume1(v.w, bi + 3, lcnt, cand);
        }
    }
}

__global__ __launch_bounds__(NT, 4) void dfine_fused_kernel(
    const float* __restrict__ logits,   // [B, Q*C]
    const float* __restrict__ pboxes,   // [B, Q, 4]  (cx, cy, w, h)
    const float* __restrict__ sizes,    // [B, 2]
    float* __restrict__ out,            // labels | boxes | scores
    int B, int Q, int C, int K)
{
    const int b   = blockIdx.x;
    const int tid = threadIdx.x;
    const int N   = Q * C;
    const int N4  = N >> 2;             // N divisible by 4 (C=80)
    const float4* __restrict__ base4 = reinterpret_cast<const float4*>(logits + (long long)b * N);

    __shared__ unsigned long long cand[CAPL];   // 32 KB
    __shared__ unsigned hist[NBINS];            // 16 KB (fallback only)
    __shared__ unsigned partial[NT];            //  4 KB (fallback only)
    __shared__ unsigned lcnt;
    __shared__ unsigned candCount;
    __shared__ unsigned threshBin;

    if (tid == 0) lcnt = 0u;
    __syncthreads();

    // ---- filter: software-pipelined phases A(7) B(7) C(6), covers N4 <= 20*NT ----
    {
        float4 va[7], vb[7], vc[6];
        #pragma unroll
        for (int j = 0; j < 7; ++j) {                    // issue A
            int i4 = j * NT + tid;
            va[j] = base4[(i4 < N4) ? i4 : (N4 - 1)];
        }
        __builtin_amdgcn_sched_barrier(0);
        #pragma unroll
        for (int j = 0; j < 7; ++j) {                    // issue B (A still in flight)
            int i4 = (7 + j) * NT + tid;
            vb[j] = base4[(i4 < N4) ? i4 : (N4 - 1)];
        }
        __builtin_amdgcn_sched_barrier(0);
        #pragma unroll
        for (int j = 0; j < 7; ++j)                      // consume A (waits vmcnt(7))
            consume4(va[j], j * NT + tid, N4, &lcnt, cand);
        __builtin_amdgcn_sched_barrier(0);
        #pragma unroll
        for (int j = 0; j < 6; ++j) {                    // issue C (B still in flight)
            int i4 = (14 + j) * NT + tid;
            vc[j] = base4[(i4 < N4) ? i4 : (N4 - 1)];
        }
        __builtin_amdgcn_sched_barrier(0);
        #pragma unroll
        for (int j = 0; j < 7; ++j)                      // consume B (waits vmcnt(6))
            consume4(vb[j], (7 + j) * NT + tid, N4, &lcnt, cand);
        __builtin_amdgcn_sched_barrier(0);
        #pragma unroll
        for (int j = 0; j < 6; ++j)                      // consume C
            consume4(vc[j], (14 + j) * NT + tid, N4, &lcnt, cand);
    }
    // generic tail for hypothetical larger shapes (no-op at N4 = 20000)
    for (int i4 = 20 * NT + tid; i4 < N4; i4 += NT)
        consume4(base4[i4], i4, N4, &lcnt, cand);
    __syncthreads();

    int n;
    const unsigned tot = lcnt;
    if (tot >= (unsigned)K && tot <= (unsigned)CAPL) {
        n = (int)tot;                               // hot path: cand[] already in LDS
    } else {
        // ---- fallback: exact histogram selection over the full batch ----
        const float* __restrict__ lg = logits + (long long)b * N;
        for (int i = tid; i < NBINS; i += NT) hist[i] = 0u;
        if (tid == 0) candCount = 0u;
        __syncthreads();
        for (int i = tid; i < N; i += NT)
            atomicAdd(&hist[f2key(lg[i]) >> 20], 1u);
        __syncthreads();
        {
            const int BPT = NBINS / NT;
            unsigned s = 0;
            #pragma unroll
            for (int m = 0; m < BPT; ++m) s += hist[tid * BPT + m];
            partial[tid] = s;
        }
        __syncthreads();
        if (tid < 64) {
            const int PPG = NT / 64;
            unsigned gs = 0;
            #pragma unroll
            for (int m = 0; m < PPG; ++m) gs += partial[tid * PPG + m];
            unsigned pre = gs;
            #pragma unroll
            for (int off = 1; off < 64; off <<= 1) {
                unsigned t = __shfl_up(pre, off);
                if (tid >= off) pre += t;
            }
            unsigned total = __shfl(pre, 63);
            unsigned suf   = total - (pre - gs);
            unsigned long long m1 = __ballot(suf >= (unsigned)K);
            int g = 63 - __clzll(m1);
            unsigned above = total - __shfl(pre, g);
            unsigned hv = hist[g * 64 + tid];
            unsigned pre2 = hv;
            #pragma unroll
            for (int off = 1; off < 64; off <<= 1) {
                unsigned t = __shfl_up(pre2, off);
                if (tid >= off) pre2 += t;
            }
            unsigned total2 = __shfl(pre2, 63);
            unsigned suf2   = above + total2 - (pre2 - hv);
            unsigned long long m2 = __ballot(suf2 >= (unsigned)K);
            int l2 = 63 - __clzll(m2);
            if (tid == 0) threshBin = (unsigned)(g * 64 + l2);
        }
        __syncthreads();
        const unsigned tb = threshBin;
        for (int i = tid; i < N; i += NT) {
            unsigned k = f2key(lg[i]);
            if ((k >> 20) >= tb) {
                unsigned p = atomicAdd(&candCount, 1u);
                if (p < (unsigned)CAPL) cand[p] = packkv(k, (unsigned)i);
            }
        }
        __syncthreads();
        n = (int)min(candCount, (unsigned)CAPL);
    }

    // ---- rank-based selection + emit ----
    const int BK = B * K;
    float* __restrict__ out_labels = out;
    float* __restrict__ out_boxes  = out + BK;
    float* __restrict__ out_scores = out + (long long)BK * 5;
    const float s0 = sizes[2 * b];
    const float s1 = sizes[2 * b + 1];

    for (int t = tid; t < n; t += NT) {
        unsigned long long my = cand[t];
        int r = 0;
        for (int j = 0; j < n; ++j) r += (cand[j] > my);   // packed keys unique
        if (r < K) {
            unsigned key = (unsigned)(my >> 32);
            unsigned idx = 0xFFFFFFFFu - (unsigned)(my & 0xFFFFFFFFull);
            float logit = key2f(key);
            float score = 1.0f / (1.0f + expf(-logit));
            int label = (int)(idx % (unsigned)C);
            int q     = (int)(idx / (unsigned)C);
            float4 bp = *reinterpret_cast<const float4*>(pboxes + ((long long)b * Q + q) * 4);
            int o = b * K + r;
            out_labels[o] = (float)label;
            out_scores[o] = score;
            float4 bb;
            bb.x = (bp.x - 0.5f * bp.z) * s0;
            bb.y = (bp.y - 0.5f * bp.w) * s1;
            bb.z = (bp.x + 0.5f * bp.z) * s0;
            bb.w = (bp.y + 0.5f * bp.w) * s1;
            *reinterpret_cast<float4*>(out_boxes + 4LL * o) = bb;
        }
    }
}

extern "C" void kernel_launch(void* const* d_in, const int* in_sizes, int n_in,
                              void* d_out, int out_size, void* d_ws, size_t ws_size,
                              hipStream_t stream) {
    const float* logits = (const float*)d_in[0];
    const float* pboxes = (const float*)d_in[1];
    const float* sizes  = (const float*)d_in[2];

    const int B = in_sizes[2] / 2;                 // 256
    const int Q = in_sizes[1] / (4 * B);           // 1000
    const int C = in_sizes[0] / (B * Q);           // 80
    const int K = out_size / (6 * B);              // 300

    dfine_fused_kernel<<<B, NT, 0, stream>>>(
        logits, pboxes, sizes, (float*)d_out, B, Q, C, K);
}

// Round 14
// 34.246 us; speedup vs baseline: 6.4957x; 1.0532x over previous
//
#include <hip/hip_runtime.h>

// D-FINE post-processor, SINGLE fused kernel: one block per batch (256 x 1024).
//   Filter (R10-exact): three burst phases (7+7+6 float4/thread, loads issued
//     before a sched_barrier, then consumed). Hits (logit > THR) compact into
//     LDS cand[] via an LDS counter. {x > THR} is a prefix of the descending
//     order, so if K <= n <= CAPL the top-K is provably contained.
//   Select (new): grouped rank-based selection -- thread t ranks candidates
//     2t and 2t+1 against the broadcast j-stream (half the LDS traffic of
//     1-per-thread), exact jax.lax.top_k tie semantics via packed
//     (key<<32)|~idx keys. Scatter-emit by rank.
//   Fallback: exact in-kernel 4096-bin histogram selection if the bound check
//     fails (any input distribution stays correct).
// Output (float32): labels [B*K] | boxes [B*K*4] | scores [B*K]

constexpr int   NT    = 1024;
constexpr int   NBINS = 4096;
constexpr int   CAPL  = 4096;   // LDS candidate capacity
constexpr float THR   = 2.5f;   // static pre-filter: ~497 hits/batch, 8.9 sigma > K

__device__ __forceinline__ unsigned f2key(float f) {
    unsigned u = __float_as_uint(f);
    return (u & 0x80000000u) ? ~u : (u | 0x80000000u);
}
__device__ __forceinline__ float key2f(unsigned k) {
    unsigned u = (k & 0x80000000u) ? (k & 0x7FFFFFFFu) : ~k;
    return __uint_as_float(u);
}
__device__ __forceinline__ unsigned long long packkv(unsigned key, unsigned idx) {
    return ((unsigned long long)key << 32) | (unsigned long long)(0xFFFFFFFFu - idx);
}

__device__ __forceinline__ void consume1(
    float x, unsigned idx, unsigned* lcnt, unsigned long long* cand)
{
    if (x > THR) {
        unsigned p = atomicAdd(lcnt, 1u);
        if (p < (unsigned)CAPL) cand[p] = packkv(f2key(x), idx);
    }
}
__device__ __forceinline__ void consume4(
    float4 v, int i4, int N4, unsigned* lcnt, unsigned long long* cand)
{
    if (i4 < N4) {
        float mx = fmaxf(fmaxf(v.x, v.y), fmaxf(v.z, v.w));
        if (mx > THR) {
            unsigned bi = (unsigned)(4 * i4);
            consume1(v.x, bi + 0, lcnt, cand);
            consume1(v.y, bi + 1, lcnt, cand);
            consume1(v.z, bi + 2, lcnt, cand);
            consume1(v.w, bi + 3, lcnt, cand);
        }
    }
}

template<int UNROLL>
__device__ __forceinline__ void filter_phase(
    const float4* __restrict__ base4, int start, int N4,
    unsigned* lcnt, unsigned long long* cand, int tid)
{
    float4 v[UNROLL];
    #pragma unroll
    for (int j = 0; j < UNROLL; ++j) {
        int i4 = start + j * NT + tid;
        int c  = (i4 < N4) ? i4 : (N4 - 1);          // clamped load, predicated use
        v[j] = base4[c];
    }
    __builtin_amdgcn_sched_barrier(0);               // all UNROLL loads in flight
    #pragma unroll
    for (int j = 0; j < UNROLL; ++j) {
        int i4 = start + j * NT + tid;
        consume4(v[j], i4, N4, lcnt, cand);
    }
}

__global__ __launch_bounds__(NT) void dfine_fused_kernel(
    const float* __restrict__ logits,   // [B, Q*C]
    const float* __restrict__ pboxes,   // [B, Q, 4]  (cx, cy, w, h)
    const float* __restrict__ sizes,    // [B, 2]
    float* __restrict__ out,            // labels | boxes | scores
    int B, int Q, int C, int K)
{
    const int b   = blockIdx.x;
    const int tid = threadIdx.x;
    const int N   = Q * C;
    const int N4  = N >> 2;             // N divisible by 4 (C=80)
    const float4* __restrict__ base4 = reinterpret_cast<const float4*>(logits + (long long)b * N);

    __shared__ unsigned long long cand[CAPL];   // 32 KB
    __shared__ unsigned hist[NBINS];            // 16 KB (fallback only)
    __shared__ unsigned partial[NT];            //  4 KB (fallback only)
    __shared__ unsigned lcnt;
    __shared__ unsigned candCount;
    __shared__ unsigned threshBin;

    if (tid == 0) lcnt = 0u;
    __syncthreads();

    // ---- filter: three burst phases (cover N4 <= 20*NT), R10-exact ----
    filter_phase<7>(base4, 0,       N4, &lcnt, cand, tid);
    filter_phase<7>(base4, 7 * NT,  N4, &lcnt, cand, tid);
    filter_phase<6>(base4, 14 * NT, N4, &lcnt, cand, tid);
    // generic tail for hypothetical larger shapes (no-op at N4 = 20000)
    for (int i4 = 20 * NT + tid; i4 < N4; i4 += NT)
        consume4(base4[i4], i4, N4, &lcnt, cand);
    __syncthreads();

    int n;
    const unsigned tot = lcnt;
    if (tot >= (unsigned)K && tot <= (unsigned)CAPL) {
        n = (int)tot;                               // hot path: cand[] already in LDS
    } else {
        // ---- fallback: exact histogram selection over the full batch ----
        const float* __restrict__ lg = logits + (long long)b * N;
        for (int i = tid; i < NBINS; i += NT) hist[i] = 0u;
        if (tid == 0) candCount = 0u;
        __syncthreads();
        for (int i = tid; i < N; i += NT)
            atomicAdd(&hist[f2key(lg[i]) >> 20], 1u);
        __syncthreads();
        {
            const int BPT = NBINS / NT;
            unsigned s = 0;
            #pragma unroll
            for (int m = 0; m < BPT; ++m) s += hist[tid * BPT + m];
            partial[tid] = s;
        }
        __syncthreads();
        if (tid < 64) {
            const int PPG = NT / 64;
            unsigned gs = 0;
            #pragma unroll
            for (int m = 0; m < PPG; ++m) gs += partial[tid * PPG + m];
            unsigned pre = gs;
            #pragma unroll
            for (int off = 1; off < 64; off <<= 1) {
                unsigned t = __shfl_up(pre, off);
                if (tid >= off) pre += t;
            }
            unsigned total = __shfl(pre, 63);
            unsigned suf   = total - (pre - gs);
            unsigned long long m1 = __ballot(suf >= (unsigned)K);
            int g = 63 - __clzll(m1);
            unsigned above = total - __shfl(pre, g);
            unsigned hv = hist[g * 64 + tid];
            unsigned pre2 = hv;
            #pragma unroll
            for (int off = 1; off < 64; off <<= 1) {
                unsigned t = __shfl_up(pre2, off);
                if (tid >= off) pre2 += t;
            }
            unsigned total2 = __shfl(pre2, 63);
            unsigned suf2   = above + total2 - (pre2 - hv);
            unsigned long long m2 = __ballot(suf2 >= (unsigned)K);
            int l2 = 63 - __clzll(m2);
            if (tid == 0) threshBin = (unsigned)(g * 64 + l2);
        }
        __syncthreads();
        const unsigned tb = threshBin;
        for (int i = tid; i < N; i += NT) {
            unsigned k = f2key(lg[i]);
            if ((k >> 20) >= tb) {
                unsigned p = atomicAdd(&candCount, 1u);
                if (p < (unsigned)CAPL) cand[p] = packkv(k, (unsigned)i);
            }
        }
        __syncthreads();
        n = (int)min(candCount, (unsigned)CAPL);
    }

    // ---- grouped rank-based selection + emit (G=2: thread t ranks 2t, 2t+1) ----
    const int BK = B * K;
    float* __restrict__ out_labels = out;
    float* __restrict__ out_boxes  = out + BK;
    float* __restrict__ out_scores = out + (long long)BK * 5;
    const float s0 = sizes[2 * b];
    const float s1 = sizes[2 * b + 1];

    for (int base = 0; base < n; base += 2 * NT) {
        int t0 = base + 2 * tid;
        if (t0 >= n) break;
        unsigned long long my0 = cand[t0];
        bool has1 = (t0 + 1) < n;
        unsigned long long my1 = has1 ? cand[t0 + 1] : 0ull;
        int r0 = 0, r1 = 0;
        for (int j = 0; j < n; ++j) {
            unsigned long long c = cand[j];       // broadcast read, shared by both ranks
            r0 += (c > my0);
            r1 += (c > my1);
        }
        #pragma unroll
        for (int g = 0; g < 2; ++g) {
            unsigned long long my = g ? my1 : my0;
            int r = g ? r1 : r0;
            if ((g == 0 || has1) && r < K) {
                unsigned key = (unsigned)(my >> 32);
                unsigned idx = 0xFFFFFFFFu - (unsigned)(my & 0xFFFFFFFFull);
                float logit = key2f(key);
                float score = 1.0f / (1.0f + expf(-logit));
                int label = (int)(idx % (unsigned)C);
                int q     = (int)(idx / (unsigned)C);
                float4 bp = *reinterpret_cast<const float4*>(pboxes + ((long long)b * Q + q) * 4);
                int o = b * K + r;
                out_labels[o] = (float)label;
                out_scores[o] = score;
                float4 bb;
                bb.x = (bp.x - 0.5f * bp.z) * s0;
                bb.y = (bp.y - 0.5f * bp.w) * s1;
                bb.z = (bp.x + 0.5f * bp.z) * s0;
                bb.w = (bp.y + 0.5f * bp.w) * s1;
                *reinterpret_cast<float4*>(out_boxes + 4LL * o) = bb;
            }
        }
    }
}

extern "C" void kernel_launch(void* const* d_in, const int* in_sizes, int n_in,
                              void* d_out, int out_size, void* d_ws, size_t ws_size,
                              hipStream_t stream) {
    const float* logits = (const float*)d_in[0];
    const float* pboxes = (const float*)d_in[1];
    const float* sizes  = (const float*)d_in[2];

    const int B = in_sizes[2] / 2;                 // 256
    const int Q = in_sizes[1] / (4 * B);           // 1000
    const int C = in_sizes[0] / (B * Q);           // 80
    const int K = out_size / (6 * B);              // 300

    dfine_fused_kernel<<<B, NT, 0, stream>>>(
        logits, pboxes, sizes, (float*)d_out, B, Q, C, K);
}